// Round 7
// baseline (583.119 us; speedup 1.0000x reference)
//
#include <hip/hip_runtime.h>

typedef __bf16 bf16;
typedef __bf16 bf16x4 __attribute__((ext_vector_type(4)));
typedef __bf16 bf16x8 __attribute__((ext_vector_type(8)));
typedef float  f32x4  __attribute__((ext_vector_type(4)));

#define HH   64
#define WW   128
#define CC   256
#define MTOK 65536   // B*H*W
#define PI_D 3.14159265358979323846

__device__ __forceinline__ int win_row(int b, int h, int w) {
  return ((b * 8 + (h >> 3)) * 16 + (w >> 3)) * 64 + ((h & 7) << 3) + (w & 7);
}

__device__ __forceinline__ void gl_lds16(const bf16* g, bf16* l) {
  __builtin_amdgcn_global_load_lds(
      (const __attribute__((address_space(1))) unsigned int*)g,
      (__attribute__((address_space(3))) unsigned int*)l, 16, 0, 0);
}

__device__ __forceinline__ float gelu_f(float v) {
  return 0.5f * v * (1.0f + erff(v * 0.70710678118654752f));
}

// ---------------------------------------------------------------------------
// Fused prologue: 6 weight transposes (f32->bf16, dst[n*K+k]=src[k*N+n]) +
// rotation grid map + zrow/biasqv init. 800 blocks.
// ---------------------------------------------------------------------------
__global__ __launch_bounds__(256) void prep_kernel(
    const float* __restrict__ wq, const float* __restrict__ wk,
    const float* __restrict__ wv, const float* __restrict__ pw,
    const float* __restrict__ f1w, const float* __restrict__ f2w,
    bf16* __restrict__ wqvT, bf16* __restrict__ wkT, bf16* __restrict__ pwT,
    bf16* __restrict__ f1T, bf16* __restrict__ f2T,
    int* __restrict__ wmap, bf16* __restrict__ zrow,
    float* __restrict__ biasqv,
    const float* __restrict__ bq, const float* __restrict__ bv) {
  const int blk = blockIdx.x;
  if (blk < 768) {
    __shared__ float tile[32][33];
    const float* src; bf16* dst; int K, N, bi;
    if (blk < 64)       { src = wq;  dst = wqvT;         K = 256;  N = 256;  bi = blk;       }
    else if (blk < 128) { src = wv;  dst = wqvT + 65536; K = 256;  N = 256;  bi = blk - 64;  }
    else if (blk < 192) { src = wk;  dst = wkT;          K = 256;  N = 256;  bi = blk - 128; }
    else if (blk < 256) { src = pw;  dst = pwT;          K = 256;  N = 256;  bi = blk - 192; }
    else if (blk < 512) { src = f1w; dst = f1T;          K = 256;  N = 1024; bi = blk - 256; }
    else                { src = f2w; dst = f2T;          K = 1024; N = 256;  bi = blk - 512; }
    const int nbk = K >> 5;
    const int bk = (bi % nbk) * 32, bn = (bi / nbk) * 32;
    const int tx = threadIdx.x & 31, ty = threadIdx.x >> 5;
#pragma unroll
    for (int r = 0; r < 4; r++)
      tile[ty + 8 * r][tx] = src[(size_t)(bk + ty + 8 * r) * N + bn + tx];
    __syncthreads();
#pragma unroll
    for (int r = 0; r < 4; r++)
      dst[(size_t)(bn + ty + 8 * r) * K + bk + tx] = (bf16)tile[tx][ty + 8 * r];
    return;
  }
  // ---- rotation grid part ----
  int p = (blk - 768) * 256 + threadIdx.x;
  if (p < 256) zrow[p] = (bf16)0.0f;
  if (p < 512) biasqv[p] = (p < 256) ? bq[p] : bv[p - 256];
  if (p >= HH * WW) return;
  int h = p >> 7, w = p & 127;
  int bh = h >> 3, i = h & 7, bw = w >> 3, j = w & 7;
  double seq_i = -0.875 + 0.25 * i;
  double seq_j = -0.875 + 0.25 * j;
  double t0 = seq_i / 8.0, t1 = seq_j / 16.0;
  double beta = ((bh + 0.5) / 4.0 - 1.0) * (PI_D / 2.0);
  double th = t0 * (PI_D / 2.0) + PI_D / 2.0;
  double ph = t1 * PI_D;
  double sb = sin(beta), cb = cos(beta);
  double st = sin(th),  ct = cos(th);
  double sp = sin(ph),  cp = cos(ph);
  double arg = -sb * st * cp + cb * ct;
  arg = fmin(1.0, fmax(-1.0, arg));
  double nth = acos(arg);
  double nph = atan2(st * sp, cb * st * cp + sb * ct);
  double lat = (nth - PI_D / 2.0) / (PI_D / 2.0);
  lat = fmin(1.0, fmax(-1.0, lat));
  double shift = 1.0 - (2.0 * bw + 1.0) / 16.0;
  double lon = nph / PI_D - shift;
  if (lon > 1.0) lon -= 2.0; else if (lon < -1.0) lon += 2.0;
  int iy = (int)rint(((lat + 1.0) * (double)HH - 1.0) * 0.5);
  int ix = (int)rint(((lon + 1.0) * (double)WW - 1.0) * 0.5);
  bool valid = (iy >= 0 && iy < HH && ix >= 0 && ix < WW);
  int dwr = ((h >> 3) * 16 + (w >> 3)) * 64 + ((h & 7) << 3) + (w & 7);
  int src = valid ? (((iy >> 3) * 16 + (ix >> 3)) * 64 + ((iy & 7) << 3) + (ix & 7)) : -1;
  wmap[dwr] = src;
}

// ---------------------------------------------------------------------------
// LayerNorm C=256 -> bf16; permute -> window-partitioned row order.
// ---------------------------------------------------------------------------
__global__ __launch_bounds__(256) void ln_kernel(const float* __restrict__ x,
                                                 const float* __restrict__ g,
                                                 const float* __restrict__ bta,
                                                 bf16* __restrict__ out,
                                                 int permute) {
  int token = blockIdx.x * 4 + (threadIdx.x >> 6);
  int lane = threadIdx.x & 63;
  const float4 v = *(const float4*)(x + (size_t)token * CC + lane * 4);
  float s  = v.x + v.y + v.z + v.w;
  float ss = v.x * v.x + v.y * v.y + v.z * v.z + v.w * v.w;
#pragma unroll
  for (int o = 32; o > 0; o >>= 1) {
    s  += __shfl_xor(s, o);
    ss += __shfl_xor(ss, o);
  }
  float mu = s * (1.0f / CC);
  float var = ss * (1.0f / CC) - mu * mu;
  float rs = rsqrtf(var + 1e-5f);
  int row = token;
  if (permute) {
    int b = token >> 13, l = token & 8191;
    row = win_row(b, l >> 7, l & 127);
  }
  int c = lane * 4;
  const float4 gv = *(const float4*)(g + c);
  const float4 bv = *(const float4*)(bta + c);
  bf16x4 o4;
  o4[0] = (bf16)((v.x - mu) * rs * gv.x + bv.x);
  o4[1] = (bf16)((v.y - mu) * rs * gv.y + bv.y);
  o4[2] = (bf16)((v.z - mu) * rs * gv.z + bv.z);
  o4[3] = (bf16)((v.w - mu) * rs * gv.w + bv.w);
  *(bf16x4*)(out + (size_t)row * CC + c) = o4;
}

// ---------------------------------------------------------------------------
// bf16 MFMA GEMM: C[M,N] = A[M,K] @ Bt[N,K]^T + bias, fused epilogues.
// 128x128 tile, BK=32, glds width=16. Grid is (mb, nb): same-mb blocks are
// gridDim.x apart in linear ID (multiple of 8) -> same XCD -> A-tile L2 reuse.
// ---------------------------------------------------------------------------
#define EPI_BF16 0
#define EPI_PROJ 2
#define EPI_QV   4

#define TRS 72  // vt transpose LDS stride

template <int EPI, bool GATHER>
__global__ __launch_bounds__(256) void gemm_bt(const bf16* __restrict__ A,
                                               const bf16* __restrict__ Bt,
                                               const float* __restrict__ bias,
                                               bf16* __restrict__ outB,
                                               float* __restrict__ outF,
                                               const float* __restrict__ res,
                                               const int* __restrict__ amap,
                                               const bf16* __restrict__ zrow,
                                               bf16* __restrict__ outB2,
                                               int M, int N, int K) {
  __shared__ bf16 lA[128 * 32];
  __shared__ bf16 lB[128 * 32];
  __shared__ bf16 trV[(EPI == EPI_QV) ? 4 * 64 * TRS : 4];
  const int t = threadIdx.x;
  const int wave = t >> 6, lane = t & 63;
  const int quad = lane >> 4, l16 = lane & 15;
  const int mb = blockIdx.x, nb = blockIdx.y;   // XCD-aware: mb fastest
  const int wm = wave >> 1, wn = wave & 1;

  f32x4 acc[4][4];
#pragma unroll
  for (int i = 0; i < 4; i++)
#pragma unroll
    for (int j = 0; j < 4; j++)
#pragma unroll
      for (int r = 0; r < 4; r++) acc[i][j][r] = 0.0f;

  const int arow = t >> 2;
  const int acol = (t & 3) << 3;
  const bf16 *gA, *gA2;
  if (GATHER) {
    int r1 = mb * 128 + arow;
    int b1 = r1 >> 13, s1 = amap[r1 & 8191];
    gA = (s1 >= 0) ? A + ((size_t)((b1 << 13) + s1)) * K + acol : zrow + acol;
    int r2 = r1 + 64;
    int b2 = r2 >> 13, s2 = amap[r2 & 8191];
    gA2 = (s2 >= 0) ? A + ((size_t)((b2 << 13) + s2)) * K + acol : zrow + acol;
  } else {
    gA = A + (size_t)(mb * 128 + arow) * K + acol;
    gA2 = gA + (size_t)64 * K;
  }
  const bf16* gB  = Bt + (size_t)(nb * 128 + arow) * K + acol;
  const bf16* gB2 = gB + (size_t)64 * K;
  bf16* lAp  = &lA[t * 8];
  bf16* lBp  = &lB[t * 8];
  bf16* lAp2 = &lA[2048 + t * 8];
  bf16* lBp2 = &lB[2048 + t * 8];

  for (int kk = 0; kk < K; kk += 32) {
    __syncthreads();
    gl_lds16(gA + kk, lAp);
    gl_lds16(gA2 + kk, lAp2);
    gl_lds16(gB + kk, lBp);
    gl_lds16(gB2 + kk, lBp2);
    __syncthreads();
    bf16x8 af[4], bfr[4];
#pragma unroll
    for (int i = 0; i < 4; i++)
      af[i] = *(const bf16x8*)&lA[(wm * 64 + i * 16 + l16) * 32 + quad * 8];
#pragma unroll
    for (int j = 0; j < 4; j++)
      bfr[j] = *(const bf16x8*)&lB[(wn * 64 + j * 16 + l16) * 32 + quad * 8];
#pragma unroll
    for (int i = 0; i < 4; i++)
#pragma unroll
      for (int j = 0; j < 4; j++)
        acc[i][j] = __builtin_amdgcn_mfma_f32_16x16x32_bf16(af[i], bfr[j], acc[i][j], 0, 0, 0);
  }

  const int m0 = mb * 128 + wm * 64;
  const int n0 = nb * 128 + wn * 64;

  if (EPI == EPI_QV && nb >= 2) {
    // ---- V: transpose through wave-private LDS, coalesced vt stores ----
    bf16* tw = &trV[wave * 64 * TRS];
#pragma unroll
    for (int i = 0; i < 4; i++)
#pragma unroll
      for (int j = 0; j < 4; j++) {
        const float bsv = bias[n0 + j * 16 + l16];
        bf16x4 pk;
#pragma unroll
        for (int r = 0; r < 4; r++) pk[r] = (bf16)(acc[i][j][r] + bsv);
        *(bf16x4*)&tw[(j * 16 + l16) * TRS + i * 16 + quad * 4] = pk;
      }
    const int win = mb * 2 + wm;
    const int chbase = n0 - 256;
#pragma unroll
    for (int s = 0; s < 8; s++) {
      const int ch = s * 8 + (lane >> 3);
      const int tk = (lane & 7) * 8;
      bf16x8 vv = *(const bf16x8*)&tw[ch * TRS + tk];
      *(bf16x8*)(outB2 + ((size_t)win * 256 + chbase + ch) * 64 + tk) = vv;
    }
  } else {
#pragma unroll
    for (int i = 0; i < 4; i++) {
#pragma unroll
      for (int j = 0; j < 4; j++) {
        const int col = n0 + j * 16 + l16;
        const int rowb = m0 + i * 16 + quad * 4;
        const float bsv = bias[col];
#pragma unroll
        for (int r = 0; r < 4; r++) {
          const int row = rowb + r;
          float v = acc[i][j][r] + bsv;
          if (EPI == EPI_BF16) {
            outB[(size_t)row * N + col] = (bf16)v;
          } else if (EPI == EPI_QV) {
            outB[(size_t)row * 256 + col] = (bf16)v;   // q, row-major
          } else {  // EPI_PROJ: window reverse + residual
            int wi = row >> 6, tt = row & 63;
            int b = wi >> 7, hb = (wi >> 4) & 7, wb = wi & 15;
            int h = hb * 8 + (tt >> 3), w = wb * 8 + (tt & 7);
            size_t idx = ((size_t)(b * 8192 + h * 128 + w)) * 256 + col;
            outF[idx] = res[idx] + v;
          }
        }
      }
    }
  }
}

// ---------------------------------------------------------------------------
// Fused MLP: out += gelu(xh @ f1 + f1b) @ f2 + f2b   (residual RMW on out).
// One block per 128 rows (512 blocks). h1 never leaves LDS: per 128-col
// chunk p, stage-1 GEMM (K=256, glds) -> gelu -> h1L[128][136] -> stage-2
// accumulates out[128x256] in registers, B-frags direct from L2-hot f2T.
// ---------------------------------------------------------------------------
#define MRS 136

__global__ __launch_bounds__(256) void mlp_kernel(const bf16* __restrict__ xh,
                                                  const bf16* __restrict__ f1T,
                                                  const float* __restrict__ f1b,
                                                  const bf16* __restrict__ f2T,
                                                  const float* __restrict__ f2b,
                                                  float* __restrict__ out) {
  __shared__ bf16 lA[128 * 32];
  __shared__ bf16 lB[128 * 32];
  __shared__ __align__(16) bf16 h1L[128 * MRS];  // 34.8 KB
  const int t = threadIdx.x;
  const int wave = t >> 6, lane = t & 63;
  const int quad = lane >> 4, l16 = lane & 15;
  const int wm = wave >> 1, wn = wave & 1;
  const int mb = blockIdx.x;
  const int arow = t >> 2, acol = (t & 3) << 3;

  const bf16* gA  = xh + (size_t)(mb * 128 + arow) * 256 + acol;
  const bf16* gA2 = gA + 64 * 256;
  bf16* lAp  = &lA[t * 8];
  bf16* lBp  = &lB[t * 8];
  bf16* lAp2 = &lA[2048 + t * 8];
  bf16* lBp2 = &lB[2048 + t * 8];

  f32x4 oacc[4][8];
#pragma unroll
  for (int i = 0; i < 4; i++)
#pragma unroll
    for (int j = 0; j < 8; j++)
#pragma unroll
      for (int r = 0; r < 4; r++) oacc[i][j][r] = 0.0f;

  for (int p = 0; p < 8; p++) {
    // ---- stage 1: h1p[128x128] = xh_tile @ f1T[p*128.., :]^T ----
    f32x4 acc[4][4];
#pragma unroll
    for (int i = 0; i < 4; i++)
#pragma unroll
      for (int j = 0; j < 4; j++)
#pragma unroll
        for (int r = 0; r < 4; r++) acc[i][j][r] = 0.0f;
    const bf16* gB  = f1T + (size_t)(p * 128 + arow) * 256 + acol;
    const bf16* gB2 = gB + 64 * 256;
    for (int kk = 0; kk < 256; kk += 32) {
      __syncthreads();
      gl_lds16(gA + kk, lAp);
      gl_lds16(gA2 + kk, lAp2);
      gl_lds16(gB + kk, lBp);
      gl_lds16(gB2 + kk, lBp2);
      __syncthreads();
      bf16x8 af[4], bfr[4];
#pragma unroll
      for (int i = 0; i < 4; i++)
        af[i] = *(const bf16x8*)&lA[(wm * 64 + i * 16 + l16) * 32 + quad * 8];
#pragma unroll
      for (int j = 0; j < 4; j++)
        bfr[j] = *(const bf16x8*)&lB[(wn * 64 + j * 16 + l16) * 32 + quad * 8];
#pragma unroll
      for (int i = 0; i < 4; i++)
#pragma unroll
        for (int j = 0; j < 4; j++)
          acc[i][j] = __builtin_amdgcn_mfma_f32_16x16x32_bf16(af[i], bfr[j], acc[i][j], 0, 0, 0);
    }
    // gelu + write h1L (C-layout -> [row][k] layout)
#pragma unroll
    for (int i = 0; i < 4; i++)
#pragma unroll
      for (int j = 0; j < 4; j++) {
        const int hcol = wn * 64 + j * 16 + l16;
        const float bsv = f1b[p * 128 + hcol];
        const int hrowb = wm * 64 + i * 16 + quad * 4;
#pragma unroll
        for (int r = 0; r < 4; r++)
          h1L[(hrowb + r) * MRS + hcol] = (bf16)gelu_f(acc[i][j][r] + bsv);
      }
    __syncthreads();
    // ---- stage 2: out[128x256] += h1p @ f2T[:, p*128..]^T ----
#pragma unroll
    for (int kc = 0; kc < 4; kc++) {
      bf16x8 af[4];
#pragma unroll
      for (int i = 0; i < 4; i++)
        af[i] = *(const bf16x8*)&h1L[(wm * 64 + i * 16 + l16) * MRS + kc * 32 + quad * 8];
#pragma unroll
      for (int j = 0; j < 8; j++) {
        bf16x8 bfr = *(const bf16x8*)(f2T + (size_t)(wn * 128 + j * 16 + l16) * 1024 +
                                      p * 128 + kc * 32 + quad * 8);
#pragma unroll
        for (int i = 0; i < 4; i++)
          oacc[i][j] = __builtin_amdgcn_mfma_f32_16x16x32_bf16(af[i], bfr, oacc[i][j], 0, 0, 0);
      }
    }
  }

  // ---- epilogue: out = res + oacc + f2b (in-place RMW) ----
#pragma unroll
  for (int i = 0; i < 4; i++)
#pragma unroll
    for (int j = 0; j < 8; j++) {
      const int col = wn * 128 + j * 16 + l16;
      const float bsv = f2b[col];
      const int rowb = mb * 128 + wm * 64 + i * 16 + quad * 4;
#pragma unroll
      for (int r = 0; r < 4; r++) {
        size_t idx = (size_t)(rowb + r) * 256 + col;
        out[idx] = out[idx] + oacc[i][j][r] + bsv;
      }
    }
}

// ---------------------------------------------------------------------------
// LePE depthwise 3x3 over qb (stride 256), window-tiled stencil. Writes ao.
// ---------------------------------------------------------------------------
__global__ __launch_bounds__(256) void lepe_kernel(const bf16* __restrict__ qb,
                                                   const float* __restrict__ rw,
                                                   const float* __restrict__ rb,
                                                   bf16* __restrict__ ao) {
  __shared__ __align__(16) bf16 hq[100 * 256];  // 51.2 KB
  const int blk = blockIdx.x;  // b*128 + hb*16 + wb
  const int b = blk >> 7, hb = (blk >> 4) & 7, wb = blk & 15;
  const int t = threadIdx.x;
  const int h0 = hb * 8 - 1, w0 = wb * 8 - 1;

  for (int idx = t; idx < 3200; idx += 256) {
    int pix = idx >> 5, ch = (idx & 31) * 8;
    int pi = pix / 10, pj = pix - pi * 10;
    int h = h0 + pi, w = w0 + pj;
    bf16x8 val;
#pragma unroll
    for (int e = 0; e < 8; e++) val[e] = (bf16)0.0f;
    if (h >= 0 && h < HH && w >= 0 && w < WW)
      val = *(const bf16x8*)(qb + (size_t)win_row(b, h, w) * 256 + ch);
    *(bf16x8*)(&hq[pix * 256 + ch]) = val;
  }
  __syncthreads();

  const int cg = t & 31, c0 = cg * 8;
  const int i = t >> 5;

  float wr[9][8];
#pragma unroll
  for (int e = 0; e < 8; e++)
#pragma unroll
    for (int tap = 0; tap < 9; tap++) wr[tap][e] = rw[(c0 + e) * 9 + tap];
  float bias[8];
  *(float4*)&bias[0] = *(const float4*)(rb + c0);
  *(float4*)&bias[4] = *(const float4*)(rb + c0 + 4);

  float cur[3][3][8];
#pragma unroll
  for (int rr = 0; rr < 3; rr++)
#pragma unroll
    for (int cc = 0; cc < 2; cc++) {
      bf16x8 v = *(const bf16x8*)(&hq[((i + rr) * 10 + cc) * 256 + c0]);
#pragma unroll
      for (int e = 0; e < 8; e++) cur[rr][cc][e] = (float)v[e];
    }

#pragma unroll
  for (int j = 0; j < 8; j++) {
    const int snew = (j + 2) % 3;
#pragma unroll
    for (int rr = 0; rr < 3; rr++) {
      bf16x8 v = *(const bf16x8*)(&hq[((i + rr) * 10 + (j + 2)) * 256 + c0]);
#pragma unroll
      for (int e = 0; e < 8; e++) cur[rr][snew][e] = (float)v[e];
    }
    float acc[8];
#pragma unroll
    for (int e = 0; e < 8; e++) acc[e] = bias[e];
#pragma unroll
    for (int rr = 0; rr < 3; rr++)
#pragma unroll
      for (int dc = 0; dc < 3; dc++) {
        const int slot = (j + dc) % 3;
        const int tap = rr * 3 + dc;
#pragma unroll
        for (int e = 0; e < 8; e++) acc[e] += cur[rr][slot][e] * wr[tap][e];
      }
    bf16x8 o;
#pragma unroll
    for (int e = 0; e < 8; e++) o[e] = (bf16)acc[e];
    *(bf16x8*)(ao + (size_t)(blk * 64 + i * 8 + j) * 256 + c0) = o;
  }
}

// ---------------------------------------------------------------------------
// MFMA windowed attention, one wave per (window, head). Grid 2048 blocks.
// ---------------------------------------------------------------------------
#define SP 74

__global__ __launch_bounds__(256) void attn_kernel(const bf16* __restrict__ qb,
                                                   const bf16* __restrict__ kb,
                                                   const bf16* __restrict__ vt,
                                                   bf16* __restrict__ ao) {
  __shared__ __align__(16) bf16 Pl[4][64 * SP];
  const int wave = threadIdx.x >> 6, lane = threadIdx.x & 63;
  const int quad = lane >> 4, l16 = lane & 15;
  const int win = blockIdx.x >> 1;
  const size_t rowbase = (size_t)win * 64;
  const int head = ((blockIdx.x & 1) << 2) + wave;
  const int hc = head * 32;
  bf16* P = Pl[wave];
  const float scale = 0.17677669529663687f;  // 32^-0.5

  bf16x8 aq[4], bk4[4];
#pragma unroll
  for (int mi = 0; mi < 4; mi++)
    aq[mi] = *(const bf16x8*)(qb + (rowbase + mi * 16 + l16) * 256 + hc + quad * 8);
#pragma unroll
  for (int ni = 0; ni < 4; ni++)
    bk4[ni] = *(const bf16x8*)(kb + (rowbase + ni * 16 + l16) * 256 + hc + quad * 8);
  f32x4 sacc[4][4];
#pragma unroll
  for (int mi = 0; mi < 4; mi++)
#pragma unroll
    for (int ni = 0; ni < 4; ni++)
#pragma unroll
      for (int r = 0; r < 4; r++) sacc[mi][ni][r] = 0.0f;
#pragma unroll
  for (int mi = 0; mi < 4; mi++)
#pragma unroll
    for (int ni = 0; ni < 4; ni++)
      sacc[mi][ni] = __builtin_amdgcn_mfma_f32_16x16x32_bf16(aq[mi], bk4[ni], sacc[mi][ni], 0, 0, 0);

  bf16x8 vb2[2][2];
#pragma unroll
  for (int n0 = 0; n0 < 2; n0++)
#pragma unroll
    for (int kc = 0; kc < 2; kc++)
      vb2[n0][kc] = *(const bf16x8*)(vt + ((size_t)win * 256 + hc + n0 * 16 + l16) * 64 +
                                     kc * 32 + quad * 8);

#pragma unroll
  for (int mi = 0; mi < 4; mi++) {
#pragma unroll
    for (int r = 0; r < 4; r++) {
      float mx = -1e30f;
#pragma unroll
      for (int ni = 0; ni < 4; ni++) mx = fmaxf(mx, sacc[mi][ni][r]);
      mx = fmaxf(mx, __shfl_xor(mx, 1));
      mx = fmaxf(mx, __shfl_xor(mx, 2));
      mx = fmaxf(mx, __shfl_xor(mx, 4));
      mx = fmaxf(mx, __shfl_xor(mx, 8));
      float sm = 0.0f;
#pragma unroll
      for (int ni = 0; ni < 4; ni++) {
        float e = expf(scale * (sacc[mi][ni][r] - mx));
        sacc[mi][ni][r] = e;
        sm += e;
      }
      sm += __shfl_xor(sm, 1);
      sm += __shfl_xor(sm, 2);
      sm += __shfl_xor(sm, 4);
      sm += __shfl_xor(sm, 8);
      float inv = 1.0f / sm;
#pragma unroll
      for (int ni = 0; ni < 4; ni++) sacc[mi][ni][r] *= inv;
    }
#pragma unroll
    for (int ni = 0; ni < 4; ni++)
#pragma unroll
      for (int r = 0; r < 4; r++)
        P[(mi * 16 + quad * 4 + r) * SP + ni * 16 + l16] = (bf16)sacc[mi][ni][r];
  }

  f32x4 oacc[4][2];
#pragma unroll
  for (int mi = 0; mi < 4; mi++)
#pragma unroll
    for (int n0 = 0; n0 < 2; n0++)
#pragma unroll
      for (int r = 0; r < 4; r++) oacc[mi][n0][r] = 0.0f;
#pragma unroll
  for (int mi = 0; mi < 4; mi++)
#pragma unroll
    for (int kc = 0; kc < 2; kc++) {
      bf16x8 pf = *(const bf16x8*)&P[(mi * 16 + l16) * SP + kc * 32 + quad * 8];
#pragma unroll
      for (int n0 = 0; n0 < 2; n0++)
        oacc[mi][n0] = __builtin_amdgcn_mfma_f32_16x16x32_bf16(pf, vb2[n0][kc], oacc[mi][n0], 0, 0, 0);
    }

  bf16* Ol = P;
#pragma unroll
  for (int mi = 0; mi < 4; mi++)
#pragma unroll
    for (int n0 = 0; n0 < 2; n0++)
#pragma unroll
      for (int r = 0; r < 4; r++)
        Ol[(mi * 16 + quad * 4 + r) * 34 + n0 * 16 + l16] = (bf16)oacc[mi][n0][r];

  bf16* aop = ao + (rowbase + lane) * 256 + hc;
#pragma unroll
  for (int cc = 0; cc < 4; cc++) {
    bf16x8 ov = *(const bf16x8*)&Ol[lane * 34 + cc * 8];
    bf16x8 lp = *(const bf16x8*)(aop + cc * 8);
    bf16x8 so;
#pragma unroll
    for (int e = 0; e < 8; e++) so[e] = (bf16)((float)ov[e] + (float)lp[e]);
    *(bf16x8*)(aop + cc * 8) = so;
  }
}

// ---------------------------------------------------------------------------
extern "C" void kernel_launch(void* const* d_in, const int* in_sizes, int n_in,
                              void* d_out, int out_size, void* d_ws, size_t ws_size,
                              hipStream_t stream) {
  const float* x     = (const float*)d_in[0];
  const float* n1g   = (const float*)d_in[3];
  const float* n1b   = (const float*)d_in[4];
  const float* wq    = (const float*)d_in[5];
  const float* bq    = (const float*)d_in[6];
  const float* wk    = (const float*)d_in[7];
  const float* bk    = (const float*)d_in[8];
  const float* wv    = (const float*)d_in[9];
  const float* bv    = (const float*)d_in[10];
  const float* rpe_w = (const float*)d_in[11];
  const float* rpe_b = (const float*)d_in[12];
  const float* pw    = (const float*)d_in[13];
  const float* pb    = (const float*)d_in[14];
  const float* n2g   = (const float*)d_in[15];
  const float* n2b   = (const float*)d_in[16];
  const float* f1w   = (const float*)d_in[17];
  const float* f1b   = (const float*)d_in[18];
  const float* f2w   = (const float*)d_in[19];
  const float* f2b   = (const float*)d_in[20];
  float* out = (float*)d_out;
  char* ws = (char*)d_ws;

  // ws layout (peak ~98 MiB):
  //   [0,  A)  xw (LN1 windowed) -> ao (lepe+attn out) -> xh (LN2 out)
  //   [A, 2A)  qb [tok][256]
  //   [2A,3A)  vt [win][ch][tok]
  //   [3A,..)  weights / wmap / zrow / biasqv (~1.7 MiB)
  // kb lives in d_out (dead before proj overwrites d_out).
  const size_t A_ = 33554432ull;
  bf16* xw  = (bf16*)(ws);
  bf16* ao  = (bf16*)(ws);
  bf16* xh  = (bf16*)(ws);
  bf16* qb  = (bf16*)(ws + A_);
  bf16* vt  = (bf16*)(ws + 2 * A_);
  bf16* kb  = (bf16*)d_out;
  char* wsp = ws + 3 * A_;
  bf16* wqvT = (bf16*)(wsp);                 // 512 x 256
  bf16* wkT  = (bf16*)(wsp + 262144);        // 256 x 256
  bf16* pwT  = (bf16*)(wsp + 393216);        // 256 x 256
  bf16* f1T  = (bf16*)(wsp + 524288);        // 1024 x 256
  bf16* f2T  = (bf16*)(wsp + 1048576);       // 256 x 1024
  float* biasqv = (float*)(wsp + 1572864);   // 512 f32
  int*   wmap   = (int*)(wsp + 1574912);     // 8192 int
  bf16*  zrow   = (bf16*)(wsp + 1607680);    // 256 bf16

  prep_kernel<<<800, 256, 0, stream>>>(wq, wk, wv, pw, f1w, f2w,
                                       wqvT, wkT, pwT, f1T, f2T,
                                       wmap, zrow, biasqv, bq, bv);

  ln_kernel<<<MTOK / 4, 256, 0, stream>>>(x, n1g, n1b, xw, 1);

  gemm_bt<EPI_QV, false><<<dim3(512, 4), 256, 0, stream>>>(
      xw, wqvT, biasqv, qb, nullptr, nullptr, nullptr, nullptr, vt, MTOK, 512, 256);
  gemm_bt<EPI_BF16, true><<<dim3(512, 2), 256, 0, stream>>>(
      xw, wkT, bk, kb, nullptr, nullptr, wmap, zrow, nullptr, MTOK, 256, 256);

  lepe_kernel<<<1024, 256, 0, stream>>>(qb, rpe_w, rpe_b, ao);
  attn_kernel<<<2048, 256, 0, stream>>>(qb, kb, vt, ao);

  gemm_bt<EPI_PROJ, false><<<dim3(512, 2), 256, 0, stream>>>(
      ao, pwT, pb, nullptr, out, x, nullptr, nullptr, nullptr, MTOK, 256, 256);

  ln_kernel<<<MTOK / 4, 256, 0, stream>>>(out, n2g, n2b, xh, 0);

  mlp_kernel<<<512, 256, 0, stream>>>(xh, f1T, f1b, f2T, f2b, out);
}

// Round 8
// 486.548 us; speedup vs baseline: 1.1985x; 1.1985x over previous
//
#include <hip/hip_runtime.h>

typedef __bf16 bf16;
typedef __bf16 bf16x4 __attribute__((ext_vector_type(4)));
typedef __bf16 bf16x8 __attribute__((ext_vector_type(8)));
typedef float  f32x4  __attribute__((ext_vector_type(4)));

#define HH   64
#define WW   128
#define CC   256
#define MTOK 65536   // B*H*W
#define PI_D 3.14159265358979323846

__device__ __forceinline__ int win_row(int b, int h, int w) {
  return ((b * 8 + (h >> 3)) * 16 + (w >> 3)) * 64 + ((h & 7) << 3) + (w & 7);
}

__device__ __forceinline__ void gl_lds16(const bf16* g, bf16* l) {
  __builtin_amdgcn_global_load_lds(
      (const __attribute__((address_space(1))) unsigned int*)g,
      (__attribute__((address_space(3))) unsigned int*)l, 16, 0, 0);
}

__device__ __forceinline__ float gelu_f(float v) {
  return 0.5f * v * (1.0f + erff(v * 0.70710678118654752f));
}

// ---------------------------------------------------------------------------
// Fused prologue: 6 weight transposes (f32->bf16, dst[n*K+k]=src[k*N+n]) +
// rotation grid map + zrow/biasqv init. 800 blocks.
// ---------------------------------------------------------------------------
__global__ __launch_bounds__(256) void prep_kernel(
    const float* __restrict__ wq, const float* __restrict__ wk,
    const float* __restrict__ wv, const float* __restrict__ pw,
    const float* __restrict__ f1w, const float* __restrict__ f2w,
    bf16* __restrict__ wqvT, bf16* __restrict__ wkT, bf16* __restrict__ pwT,
    bf16* __restrict__ f1T, bf16* __restrict__ f2T,
    int* __restrict__ wmap, bf16* __restrict__ zrow,
    float* __restrict__ biasqv,
    const float* __restrict__ bq, const float* __restrict__ bv) {
  const int blk = blockIdx.x;
  if (blk < 768) {
    __shared__ float tile[32][33];
    const float* src; bf16* dst; int K, N, bi;
    if (blk < 64)       { src = wq;  dst = wqvT;         K = 256;  N = 256;  bi = blk;       }
    else if (blk < 128) { src = wv;  dst = wqvT + 65536; K = 256;  N = 256;  bi = blk - 64;  }
    else if (blk < 192) { src = wk;  dst = wkT;          K = 256;  N = 256;  bi = blk - 128; }
    else if (blk < 256) { src = pw;  dst = pwT;          K = 256;  N = 256;  bi = blk - 192; }
    else if (blk < 512) { src = f1w; dst = f1T;          K = 256;  N = 1024; bi = blk - 256; }
    else                { src = f2w; dst = f2T;          K = 1024; N = 256;  bi = blk - 512; }
    const int nbk = K >> 5;
    const int bk = (bi % nbk) * 32, bn = (bi / nbk) * 32;
    const int tx = threadIdx.x & 31, ty = threadIdx.x >> 5;
#pragma unroll
    for (int r = 0; r < 4; r++)
      tile[ty + 8 * r][tx] = src[(size_t)(bk + ty + 8 * r) * N + bn + tx];
    __syncthreads();
#pragma unroll
    for (int r = 0; r < 4; r++)
      dst[(size_t)(bn + ty + 8 * r) * K + bk + tx] = (bf16)tile[tx][ty + 8 * r];
    return;
  }
  // ---- rotation grid part ----
  int p = (blk - 768) * 256 + threadIdx.x;
  if (p < 256) zrow[p] = (bf16)0.0f;
  if (p < 512) biasqv[p] = (p < 256) ? bq[p] : bv[p - 256];
  if (p >= HH * WW) return;
  int h = p >> 7, w = p & 127;
  int bh = h >> 3, i = h & 7, bw = w >> 3, j = w & 7;
  double seq_i = -0.875 + 0.25 * i;
  double seq_j = -0.875 + 0.25 * j;
  double t0 = seq_i / 8.0, t1 = seq_j / 16.0;
  double beta = ((bh + 0.5) / 4.0 - 1.0) * (PI_D / 2.0);
  double th = t0 * (PI_D / 2.0) + PI_D / 2.0;
  double ph = t1 * PI_D;
  double sb = sin(beta), cb = cos(beta);
  double st = sin(th),  ct = cos(th);
  double sp = sin(ph),  cp = cos(ph);
  double arg = -sb * st * cp + cb * ct;
  arg = fmin(1.0, fmax(-1.0, arg));
  double nth = acos(arg);
  double nph = atan2(st * sp, cb * st * cp + sb * ct);
  double lat = (nth - PI_D / 2.0) / (PI_D / 2.0);
  lat = fmin(1.0, fmax(-1.0, lat));
  double shift = 1.0 - (2.0 * bw + 1.0) / 16.0;
  double lon = nph / PI_D - shift;
  if (lon > 1.0) lon -= 2.0; else if (lon < -1.0) lon += 2.0;
  int iy = (int)rint(((lat + 1.0) * (double)HH - 1.0) * 0.5);
  int ix = (int)rint(((lon + 1.0) * (double)WW - 1.0) * 0.5);
  bool valid = (iy >= 0 && iy < HH && ix >= 0 && ix < WW);
  int dwr = ((h >> 3) * 16 + (w >> 3)) * 64 + ((h & 7) << 3) + (w & 7);
  int src = valid ? (((iy >> 3) * 16 + (ix >> 3)) * 64 + ((iy & 7) << 3) + (ix & 7)) : -1;
  wmap[dwr] = src;
}

// ---------------------------------------------------------------------------
// LayerNorm C=256 -> bf16; permute -> window-partitioned row order.
// ---------------------------------------------------------------------------
__global__ __launch_bounds__(256) void ln_kernel(const float* __restrict__ x,
                                                 const float* __restrict__ g,
                                                 const float* __restrict__ bta,
                                                 bf16* __restrict__ out,
                                                 int permute) {
  int token = blockIdx.x * 4 + (threadIdx.x >> 6);
  int lane = threadIdx.x & 63;
  const float4 v = *(const float4*)(x + (size_t)token * CC + lane * 4);
  float s  = v.x + v.y + v.z + v.w;
  float ss = v.x * v.x + v.y * v.y + v.z * v.z + v.w * v.w;
#pragma unroll
  for (int o = 32; o > 0; o >>= 1) {
    s  += __shfl_xor(s, o);
    ss += __shfl_xor(ss, o);
  }
  float mu = s * (1.0f / CC);
  float var = ss * (1.0f / CC) - mu * mu;
  float rs = rsqrtf(var + 1e-5f);
  int row = token;
  if (permute) {
    int b = token >> 13, l = token & 8191;
    row = win_row(b, l >> 7, l & 127);
  }
  int c = lane * 4;
  const float4 gv = *(const float4*)(g + c);
  const float4 bv = *(const float4*)(bta + c);
  bf16x4 o4;
  o4[0] = (bf16)((v.x - mu) * rs * gv.x + bv.x);
  o4[1] = (bf16)((v.y - mu) * rs * gv.y + bv.y);
  o4[2] = (bf16)((v.z - mu) * rs * gv.z + bv.z);
  o4[3] = (bf16)((v.w - mu) * rs * gv.w + bv.w);
  *(bf16x4*)(out + (size_t)row * CC + c) = o4;
}

// ---------------------------------------------------------------------------
// bf16 MFMA GEMM: C[M,N] = A[M,K] @ Bt[N,K]^T + bias, fused epilogues.
// 128x128 tile, BK=32, glds width=16. Grid (mb, nb): same-nb blocks are
// contiguous in mb with stride gridDim.x % 8 == 0 -> same-A-tile blocks
// share an XCD for L2 reuse.
// ---------------------------------------------------------------------------
#define EPI_BF16 0
#define EPI_GELU 1
#define EPI_PROJ 2
#define EPI_FC2  3
#define EPI_QV   4

#define TRS 72  // vt transpose LDS stride

template <int EPI, bool GATHER>
__global__ __launch_bounds__(256) void gemm_bt(const bf16* __restrict__ A,
                                               const bf16* __restrict__ Bt,
                                               const float* __restrict__ bias,
                                               bf16* __restrict__ outB,
                                               float* __restrict__ outF,
                                               const float* __restrict__ res,
                                               const int* __restrict__ amap,
                                               const bf16* __restrict__ zrow,
                                               bf16* __restrict__ outB2,
                                               int M, int N, int K) {
  __shared__ bf16 lA[128 * 32];
  __shared__ bf16 lB[128 * 32];
  __shared__ bf16 trV[(EPI == EPI_QV) ? 4 * 64 * TRS : 4];
  const int t = threadIdx.x;
  const int wave = t >> 6, lane = t & 63;
  const int quad = lane >> 4, l16 = lane & 15;
  const int mb = blockIdx.x, nb = blockIdx.y;   // XCD-aware: mb fastest
  const int wm = wave >> 1, wn = wave & 1;

  f32x4 acc[4][4];
#pragma unroll
  for (int i = 0; i < 4; i++)
#pragma unroll
    for (int j = 0; j < 4; j++)
#pragma unroll
      for (int r = 0; r < 4; r++) acc[i][j][r] = 0.0f;

  const int arow = t >> 2;
  const int acol = (t & 3) << 3;
  const bf16 *gA, *gA2;
  if (GATHER) {
    int r1 = mb * 128 + arow;
    int b1 = r1 >> 13, s1 = amap[r1 & 8191];
    gA = (s1 >= 0) ? A + ((size_t)((b1 << 13) + s1)) * K + acol : zrow + acol;
    int r2 = r1 + 64;
    int b2 = r2 >> 13, s2 = amap[r2 & 8191];
    gA2 = (s2 >= 0) ? A + ((size_t)((b2 << 13) + s2)) * K + acol : zrow + acol;
  } else {
    gA = A + (size_t)(mb * 128 + arow) * K + acol;
    gA2 = gA + (size_t)64 * K;
  }
  const bf16* gB  = Bt + (size_t)(nb * 128 + arow) * K + acol;
  const bf16* gB2 = gB + (size_t)64 * K;
  bf16* lAp  = &lA[t * 8];
  bf16* lBp  = &lB[t * 8];
  bf16* lAp2 = &lA[2048 + t * 8];
  bf16* lBp2 = &lB[2048 + t * 8];

  for (int kk = 0; kk < K; kk += 32) {
    __syncthreads();
    gl_lds16(gA + kk, lAp);
    gl_lds16(gA2 + kk, lAp2);
    gl_lds16(gB + kk, lBp);
    gl_lds16(gB2 + kk, lBp2);
    __syncthreads();
    bf16x8 af[4], bfr[4];
#pragma unroll
    for (int i = 0; i < 4; i++)
      af[i] = *(const bf16x8*)&lA[(wm * 64 + i * 16 + l16) * 32 + quad * 8];
#pragma unroll
    for (int j = 0; j < 4; j++)
      bfr[j] = *(const bf16x8*)&lB[(wn * 64 + j * 16 + l16) * 32 + quad * 8];
#pragma unroll
    for (int i = 0; i < 4; i++)
#pragma unroll
      for (int j = 0; j < 4; j++)
        acc[i][j] = __builtin_amdgcn_mfma_f32_16x16x32_bf16(af[i], bfr[j], acc[i][j], 0, 0, 0);
  }

  const int m0 = mb * 128 + wm * 64;
  const int n0 = nb * 128 + wn * 64;

  if (EPI == EPI_QV && nb >= 2) {
    // ---- V: transpose through wave-private LDS, coalesced vt stores ----
    bf16* tw = &trV[wave * 64 * TRS];
#pragma unroll
    for (int i = 0; i < 4; i++)
#pragma unroll
      for (int j = 0; j < 4; j++) {
        const float bsv = bias[n0 + j * 16 + l16];
        bf16x4 pk;
#pragma unroll
        for (int r = 0; r < 4; r++) pk[r] = (bf16)(acc[i][j][r] + bsv);
        *(bf16x4*)&tw[(j * 16 + l16) * TRS + i * 16 + quad * 4] = pk;
      }
    const int win = mb * 2 + wm;
    const int chbase = n0 - 256;
#pragma unroll
    for (int s = 0; s < 8; s++) {
      const int ch = s * 8 + (lane >> 3);
      const int tk = (lane & 7) * 8;
      bf16x8 vv = *(const bf16x8*)&tw[ch * TRS + tk];
      *(bf16x8*)(outB2 + ((size_t)win * 256 + chbase + ch) * 64 + tk) = vv;
    }
  } else {
#pragma unroll
    for (int i = 0; i < 4; i++) {
#pragma unroll
      for (int j = 0; j < 4; j++) {
        const int col = n0 + j * 16 + l16;
        const int rowb = m0 + i * 16 + quad * 4;
        const float bsv = bias[col];
#pragma unroll
        for (int r = 0; r < 4; r++) {
          const int row = rowb + r;
          float v = acc[i][j][r] + bsv;
          if (EPI == EPI_BF16) {
            outB[(size_t)row * N + col] = (bf16)v;
          } else if (EPI == EPI_QV) {
            outB[(size_t)row * 256 + col] = (bf16)v;   // q, row-major
          } else if (EPI == EPI_GELU) {
            outB[(size_t)row * N + col] = (bf16)gelu_f(v);
          } else if (EPI == EPI_FC2) {
            size_t idx = (size_t)row * N + col;
            outF[idx] = res[idx] + v;
          } else {  // EPI_PROJ: window reverse + residual
            int wi = row >> 6, tt = row & 63;
            int b = wi >> 7, hb = (wi >> 4) & 7, wb = wi & 15;
            int h = hb * 8 + (tt >> 3), w = wb * 8 + (tt & 7);
            size_t idx = ((size_t)(b * 8192 + h * 128 + w)) * 256 + col;
            outF[idx] = res[idx] + v;
          }
        }
      }
    }
  }
}

// ---------------------------------------------------------------------------
// LePE depthwise 3x3 over qb (stride 256), window-tiled stencil. Writes ao.
// ---------------------------------------------------------------------------
__global__ __launch_bounds__(256) void lepe_kernel(const bf16* __restrict__ qb,
                                                   const float* __restrict__ rw,
                                                   const float* __restrict__ rb,
                                                   bf16* __restrict__ ao) {
  __shared__ __align__(16) bf16 hq[100 * 256];  // 51.2 KB
  const int blk = blockIdx.x;  // b*128 + hb*16 + wb
  const int b = blk >> 7, hb = (blk >> 4) & 7, wb = blk & 15;
  const int t = threadIdx.x;
  const int h0 = hb * 8 - 1, w0 = wb * 8 - 1;

  for (int idx = t; idx < 3200; idx += 256) {
    int pix = idx >> 5, ch = (idx & 31) * 8;
    int pi = pix / 10, pj = pix - pi * 10;
    int h = h0 + pi, w = w0 + pj;
    bf16x8 val;
#pragma unroll
    for (int e = 0; e < 8; e++) val[e] = (bf16)0.0f;
    if (h >= 0 && h < HH && w >= 0 && w < WW)
      val = *(const bf16x8*)(qb + (size_t)win_row(b, h, w) * 256 + ch);
    *(bf16x8*)(&hq[pix * 256 + ch]) = val;
  }
  __syncthreads();

  const int cg = t & 31, c0 = cg * 8;
  const int i = t >> 5;

  float wr[9][8];
#pragma unroll
  for (int e = 0; e < 8; e++)
#pragma unroll
    for (int tap = 0; tap < 9; tap++) wr[tap][e] = rw[(c0 + e) * 9 + tap];
  float bias[8];
  *(float4*)&bias[0] = *(const float4*)(rb + c0);
  *(float4*)&bias[4] = *(const float4*)(rb + c0 + 4);

  float cur[3][3][8];
#pragma unroll
  for (int rr = 0; rr < 3; rr++)
#pragma unroll
    for (int cc = 0; cc < 2; cc++) {
      bf16x8 v = *(const bf16x8*)(&hq[((i + rr) * 10 + cc) * 256 + c0]);
#pragma unroll
      for (int e = 0; e < 8; e++) cur[rr][cc][e] = (float)v[e];
    }

#pragma unroll
  for (int j = 0; j < 8; j++) {
    const int snew = (j + 2) % 3;
#pragma unroll
    for (int rr = 0; rr < 3; rr++) {
      bf16x8 v = *(const bf16x8*)(&hq[((i + rr) * 10 + (j + 2)) * 256 + c0]);
#pragma unroll
      for (int e = 0; e < 8; e++) cur[rr][snew][e] = (float)v[e];
    }
    float acc[8];
#pragma unroll
    for (int e = 0; e < 8; e++) acc[e] = bias[e];
#pragma unroll
    for (int rr = 0; rr < 3; rr++)
#pragma unroll
      for (int dc = 0; dc < 3; dc++) {
        const int slot = (j + dc) % 3;
        const int tap = rr * 3 + dc;
#pragma unroll
        for (int e = 0; e < 8; e++) acc[e] += cur[rr][slot][e] * wr[tap][e];
      }
    bf16x8 o;
#pragma unroll
    for (int e = 0; e < 8; e++) o[e] = (bf16)acc[e];
    *(bf16x8*)(ao + (size_t)(blk * 64 + i * 8 + j) * 256 + c0) = o;
  }
}

// ---------------------------------------------------------------------------
// MFMA windowed attention, one wave per (window, head). Grid 2048 blocks.
// ---------------------------------------------------------------------------
#define SP 74

__global__ __launch_bounds__(256) void attn_kernel(const bf16* __restrict__ qb,
                                                   const bf16* __restrict__ kb,
                                                   const bf16* __restrict__ vt,
                                                   bf16* __restrict__ ao) {
  __shared__ __align__(16) bf16 Pl[4][64 * SP];
  const int wave = threadIdx.x >> 6, lane = threadIdx.x & 63;
  const int quad = lane >> 4, l16 = lane & 15;
  const int win = blockIdx.x >> 1;
  const size_t rowbase = (size_t)win * 64;
  const int head = ((blockIdx.x & 1) << 2) + wave;
  const int hc = head * 32;
  bf16* P = Pl[wave];
  const float scale = 0.17677669529663687f;  // 32^-0.5

  bf16x8 aq[4], bk4[4];
#pragma unroll
  for (int mi = 0; mi < 4; mi++)
    aq[mi] = *(const bf16x8*)(qb + (rowbase + mi * 16 + l16) * 256 + hc + quad * 8);
#pragma unroll
  for (int ni = 0; ni < 4; ni++)
    bk4[ni] = *(const bf16x8*)(kb + (rowbase + ni * 16 + l16) * 256 + hc + quad * 8);
  f32x4 sacc[4][4];
#pragma unroll
  for (int mi = 0; mi < 4; mi++)
#pragma unroll
    for (int ni = 0; ni < 4; ni++)
#pragma unroll
      for (int r = 0; r < 4; r++) sacc[mi][ni][r] = 0.0f;
#pragma unroll
  for (int mi = 0; mi < 4; mi++)
#pragma unroll
    for (int ni = 0; ni < 4; ni++)
      sacc[mi][ni] = __builtin_amdgcn_mfma_f32_16x16x32_bf16(aq[mi], bk4[ni], sacc[mi][ni], 0, 0, 0);

  bf16x8 vb2[2][2];
#pragma unroll
  for (int n0 = 0; n0 < 2; n0++)
#pragma unroll
    for (int kc = 0; kc < 2; kc++)
      vb2[n0][kc] = *(const bf16x8*)(vt + ((size_t)win * 256 + hc + n0 * 16 + l16) * 64 +
                                     kc * 32 + quad * 8);

#pragma unroll
  for (int mi = 0; mi < 4; mi++) {
#pragma unroll
    for (int r = 0; r < 4; r++) {
      float mx = -1e30f;
#pragma unroll
      for (int ni = 0; ni < 4; ni++) mx = fmaxf(mx, sacc[mi][ni][r]);
      mx = fmaxf(mx, __shfl_xor(mx, 1));
      mx = fmaxf(mx, __shfl_xor(mx, 2));
      mx = fmaxf(mx, __shfl_xor(mx, 4));
      mx = fmaxf(mx, __shfl_xor(mx, 8));
      float sm = 0.0f;
#pragma unroll
      for (int ni = 0; ni < 4; ni++) {
        float e = expf(scale * (sacc[mi][ni][r] - mx));
        sacc[mi][ni][r] = e;
        sm += e;
      }
      sm += __shfl_xor(sm, 1);
      sm += __shfl_xor(sm, 2);
      sm += __shfl_xor(sm, 4);
      sm += __shfl_xor(sm, 8);
      float inv = 1.0f / sm;
#pragma unroll
      for (int ni = 0; ni < 4; ni++) sacc[mi][ni][r] *= inv;
    }
#pragma unroll
    for (int ni = 0; ni < 4; ni++)
#pragma unroll
      for (int r = 0; r < 4; r++)
        P[(mi * 16 + quad * 4 + r) * SP + ni * 16 + l16] = (bf16)sacc[mi][ni][r];
  }

  f32x4 oacc[4][2];
#pragma unroll
  for (int mi = 0; mi < 4; mi++)
#pragma unroll
    for (int n0 = 0; n0 < 2; n0++)
#pragma unroll
      for (int r = 0; r < 4; r++) oacc[mi][n0][r] = 0.0f;
#pragma unroll
  for (int mi = 0; mi < 4; mi++)
#pragma unroll
    for (int kc = 0; kc < 2; kc++) {
      bf16x8 pf = *(const bf16x8*)&P[(mi * 16 + l16) * SP + kc * 32 + quad * 8];
#pragma unroll
      for (int n0 = 0; n0 < 2; n0++)
        oacc[mi][n0] = __builtin_amdgcn_mfma_f32_16x16x32_bf16(pf, vb2[n0][kc], oacc[mi][n0], 0, 0, 0);
    }

  bf16* Ol = P;
#pragma unroll
  for (int mi = 0; mi < 4; mi++)
#pragma unroll
    for (int n0 = 0; n0 < 2; n0++)
#pragma unroll
      for (int r = 0; r < 4; r++)
        Ol[(mi * 16 + quad * 4 + r) * 34 + n0 * 16 + l16] = (bf16)oacc[mi][n0][r];

  bf16* aop = ao + (rowbase + lane) * 256 + hc;
#pragma unroll
  for (int cc = 0; cc < 4; cc++) {
    bf16x8 ov = *(const bf16x8*)&Ol[lane * 34 + cc * 8];
    bf16x8 lp = *(const bf16x8*)(aop + cc * 8);
    bf16x8 so;
#pragma unroll
    for (int e = 0; e < 8; e++) so[e] = (bf16)((float)ov[e] + (float)lp[e]);
    *(bf16x8*)(aop + cc * 8) = so;
  }
}

// ---------------------------------------------------------------------------
extern "C" void kernel_launch(void* const* d_in, const int* in_sizes, int n_in,
                              void* d_out, int out_size, void* d_ws, size_t ws_size,
                              hipStream_t stream) {
  const float* x     = (const float*)d_in[0];
  const float* n1g   = (const float*)d_in[3];
  const float* n1b   = (const float*)d_in[4];
  const float* wq    = (const float*)d_in[5];
  const float* bq    = (const float*)d_in[6];
  const float* wk    = (const float*)d_in[7];
  const float* bk    = (const float*)d_in[8];
  const float* wv    = (const float*)d_in[9];
  const float* bv    = (const float*)d_in[10];
  const float* rpe_w = (const float*)d_in[11];
  const float* rpe_b = (const float*)d_in[12];
  const float* pw    = (const float*)d_in[13];
  const float* pb    = (const float*)d_in[14];
  const float* n2g   = (const float*)d_in[15];
  const float* n2b   = (const float*)d_in[16];
  const float* f1w   = (const float*)d_in[17];
  const float* f1b   = (const float*)d_in[18];
  const float* f2w   = (const float*)d_in[19];
  const float* f2b   = (const float*)d_in[20];
  float* out = (float*)d_out;
  char* ws = (char*)d_ws;

  // ws layout (peak ~98 MiB):
  //   [0,  A)  xw (LN1 windowed) -> ao (lepe+attn out) -> xh (LN2 out)
  //   [A, 2A)  qb [tok][256]     -> h1 chunk (32768 x 1024 bf16 spans [A,3A))
  //   [2A,3A)  vt [win][ch][tok]
  //   [3A,..)  weights / wmap / zrow / biasqv (~1.7 MiB)
  // kb lives in d_out (dead before proj overwrites d_out).
  const size_t A_ = 33554432ull;
  bf16* xw  = (bf16*)(ws);
  bf16* ao  = (bf16*)(ws);
  bf16* xh  = (bf16*)(ws);
  bf16* qb  = (bf16*)(ws + A_);
  bf16* vt  = (bf16*)(ws + 2 * A_);
  bf16* h1  = (bf16*)(ws + A_);
  bf16* kb  = (bf16*)d_out;
  char* wsp = ws + 3 * A_;
  bf16* wqvT = (bf16*)(wsp);                 // 512 x 256
  bf16* wkT  = (bf16*)(wsp + 262144);        // 256 x 256
  bf16* pwT  = (bf16*)(wsp + 393216);        // 256 x 256
  bf16* f1T  = (bf16*)(wsp + 524288);        // 1024 x 256
  bf16* f2T  = (bf16*)(wsp + 1048576);       // 256 x 1024
  float* biasqv = (float*)(wsp + 1572864);   // 512 f32
  int*   wmap   = (int*)(wsp + 1574912);     // 8192 int
  bf16*  zrow   = (bf16*)(wsp + 1607680);    // 256 bf16

  prep_kernel<<<800, 256, 0, stream>>>(wq, wk, wv, pw, f1w, f2w,
                                       wqvT, wkT, pwT, f1T, f2T,
                                       wmap, zrow, biasqv, bq, bv);

  ln_kernel<<<MTOK / 4, 256, 0, stream>>>(x, n1g, n1b, xw, 1);

  gemm_bt<EPI_QV, false><<<dim3(512, 4), 256, 0, stream>>>(
      xw, wqvT, biasqv, qb, nullptr, nullptr, nullptr, nullptr, vt, MTOK, 512, 256);
  gemm_bt<EPI_BF16, true><<<dim3(512, 2), 256, 0, stream>>>(
      xw, wkT, bk, kb, nullptr, nullptr, wmap, zrow, nullptr, MTOK, 256, 256);

  lepe_kernel<<<1024, 256, 0, stream>>>(qb, rpe_w, rpe_b, ao);
  attn_kernel<<<2048, 256, 0, stream>>>(qb, kb, vt, ao);

  gemm_bt<EPI_PROJ, false><<<dim3(512, 2), 256, 0, stream>>>(
      ao, pwT, pb, nullptr, out, x, nullptr, nullptr, nullptr, MTOK, 256, 256);

  ln_kernel<<<MTOK / 4, 256, 0, stream>>>(out, n2g, n2b, xh, 0);

  // MLP in 2 row-chunks (h1 chunk spans [A,3A), reusing qb+vt slabs)
  const int CH = 32768;
  for (int c = 0; c < 2; c++) {
    gemm_bt<EPI_GELU, false><<<dim3(CH / 128, 8), 256, 0, stream>>>(
        xh + (size_t)c * CH * 256, f1T, f1b, h1, nullptr, nullptr, nullptr, nullptr, nullptr,
        CH, 1024, 256);
    gemm_bt<EPI_FC2, false><<<dim3(CH / 128, 2), 256, 0, stream>>>(
        h1, f2T, f2b, nullptr, out + (size_t)c * CH * 256, out + (size_t)c * CH * 256,
        nullptr, nullptr, nullptr, CH, 256, 1024);
  }
}